// Round 1
// baseline (254.878 us; speedup 1.0000x reference)
//
#include <hip/hip_runtime.h>

#define B_   4
#define C_   2048
#define HW_  196
#define P_   784      // B_*HW_
#define NCLS 80
#define WD   300
#define ID   1024

// workspace layout (float offsets)
#define WP_OFF   0          // word_p [80][1024]
#define V_OFF    81920      // v [1024]
#define BS_OFF   82944      // bs [1]
#define IMGP_OFF 83968      // img_p [784][1024]
#define LG_OFF   886784     // logits [784][80]
#define SM_OFF   949504     // softmax [4][80][196]

__device__ __forceinline__ float fast_tanh(float x) {
    // tanh(x) = 1 - 2/(e^{2x}+1);  v_exp + v_rcp, ~1e-6 abs error
    float e = __expf(2.0f * x);
    return 1.0f - 2.0f * __builtin_amdgcn_rcpf(e + 1.0f);
}

// ---- K1: word_p[n][d] = sum_k wf[n,k]*fc2w[d,k] ----
__global__ __launch_bounds__(256) void k_wordp(const float* __restrict__ wf,
                                               const float* __restrict__ fc2w,
                                               float* __restrict__ wp) {
    int idx = blockIdx.x * 256 + threadIdx.x;   // 0..81919, idx = n*1024+d
    int n = idx >> 10, d = idx & 1023;
    const float4* a = (const float4*)(wf + n * WD);
    const float4* b = (const float4*)(fc2w + d * WD);
    float s = 0.f;
    #pragma unroll 5
    for (int k = 0; k < WD / 4; ++k) {
        float4 x = a[k], y = b[k];
        s += x.x * y.x + x.y * y.y + x.z * y.z + x.w * y.w;
    }
    wp[idx] = s;
}

// ---- K2: v[d] += sum_e fc4w[e]*fc3w[e,d] (atomic over e-chunks) ----
__global__ __launch_bounds__(256) void k_v(const float* __restrict__ fc3w,
                                           const float* __restrict__ fc4w,
                                           float* __restrict__ v) {
    int d  = blockIdx.x * 256 + threadIdx.x;
    int e0 = blockIdx.y * 64;
    float s = 0.f;
    #pragma unroll 8
    for (int e = e0; e < e0 + 64; ++e) s += fc4w[e] * fc3w[e * ID + d];
    atomicAdd(&v[d], s);
}

// ---- K2b: bs = dot(fc3b, fc4w) + fc4b ----
__global__ __launch_bounds__(256) void k_bs(const float* __restrict__ fc3b,
                                            const float* __restrict__ fc4w,
                                            const float* __restrict__ fc4b,
                                            float* __restrict__ bs) {
    __shared__ float red[256];
    int t = threadIdx.x;
    float s = 0.f;
    for (int i = t; i < ID; i += 256) s += fc3b[i] * fc4w[i];
    red[t] = s; __syncthreads();
    for (int o = 128; o > 0; o >>= 1) { if (t < o) red[t] += red[t + o]; __syncthreads(); }
    if (t == 0) bs[0] = red[0] + fc4b[0];
}

// ---- K3: img_p[p][d] = sum_c img[b,c,hw]*fc1w[d,c]; 64x64 tile, split-K=4 ----
#define KC 32
__global__ __launch_bounds__(256) void k_fc1(const float* __restrict__ img,
                                             const float* __restrict__ fc1w,
                                             float* __restrict__ imgp) {
    __shared__ float As[KC * 64];   // [c][p]
    __shared__ float Bs[KC * 68];   // [c][d], pad 68 for bank + 16B align
    int t  = threadIdx.x;
    int bx = blockIdx.x, by = blockIdx.y, bz = blockIdx.z;
    int tr = t >> 4, tc = t & 15;
    float acc[4][4] = {};

    int p_l = t & 63;            // A-load: row within tile
    int cA0 = (t >> 6) * 8;      // A-load: c start
    int cB  = t & 31;            // B-load: c
    int dB0 = (t >> 5) * 8;      // B-load: d start

    int p  = bx * 64 + p_l;
    int pc = p < P_ ? p : P_ - 1;
    int bb = pc / HW_, hw = pc % HW_;
    bool pval = (p < P_);

    for (int kc = 0; kc < 512 / KC; ++kc) {
        int c_base = bz * 512 + kc * KC;
        __syncthreads();
        #pragma unroll
        for (int j = 0; j < 8; ++j) {
            int c = c_base + cA0 + j;
            float val = pval ? img[(bb * C_ + c) * HW_ + hw] : 0.f;
            As[(cA0 + j) * 64 + p_l] = val;
        }
        #pragma unroll
        for (int j = 0; j < 8; ++j) {
            int d = by * 64 + dB0 + j;
            Bs[cB * 68 + dB0 + j] = fc1w[d * C_ + c_base + cB];
        }
        __syncthreads();
        #pragma unroll
        for (int c = 0; c < KC; ++c) {
            float4 av = *(const float4*)&As[c * 64 + tr * 4];
            float4 bv = *(const float4*)&Bs[c * 68 + tc * 4];
            float a[4] = {av.x, av.y, av.z, av.w};
            float b[4] = {bv.x, bv.y, bv.z, bv.w};
            #pragma unroll
            for (int i = 0; i < 4; ++i)
                #pragma unroll
                for (int j = 0; j < 4; ++j)
                    acc[i][j] += a[i] * b[j];
        }
    }
    #pragma unroll
    for (int i = 0; i < 4; ++i) {
        int pp = bx * 64 + tr * 4 + i;
        if (pp < P_) {
            #pragma unroll
            for (int j = 0; j < 4; ++j)
                atomicAdd(&imgp[pp * ID + by * 64 + tc * 4 + j], acc[i][j]);
        }
    }
}

// ---- K4: logits[p][n] = sum_d tanh(img_p[p,d]*word_p[n,d])*v[d] + bs ----
__global__ __launch_bounds__(256) void k_logits(const float* __restrict__ imgp,
                                                const float* __restrict__ wp,
                                                const float* __restrict__ v,
                                                const float* __restrict__ bs,
                                                float* __restrict__ lg) {
    int p = blockIdx.x;
    int wave = threadIdx.x >> 6, lane = threadIdx.x & 63;
    int n = blockIdx.y * 4 + wave;
    const float4* a4 = (const float4*)(imgp + p * ID);
    const float4* w4 = (const float4*)(wp + n * ID);
    const float4* v4 = (const float4*)v;
    float s = 0.f;
    #pragma unroll
    for (int it = 0; it < 4; ++it) {
        int i = it * 64 + lane;
        float4 a = a4[i], w = w4[i], vv = v4[i];
        s += fast_tanh(a.x * w.x) * vv.x;
        s += fast_tanh(a.y * w.y) * vv.y;
        s += fast_tanh(a.z * w.z) * vv.z;
        s += fast_tanh(a.w * w.w) * vv.w;
    }
    #pragma unroll
    for (int off = 32; off > 0; off >>= 1) s += __shfl_xor(s, off, 64);
    if (lane == 0) lg[p * NCLS + n] = s + bs[0];
}

// ---- K5: softmax over 196 positions per (b,n); write [b][n][hw] ----
__global__ __launch_bounds__(256) void k_softmax(const float* __restrict__ lg,
                                                 float* __restrict__ sm) {
    __shared__ float red[256];
    int b = blockIdx.x, n = blockIdx.y, t = threadIdx.x;
    float x = (t < HW_) ? lg[(b * HW_ + t) * NCLS + n] : -1e30f;
    red[t] = x; __syncthreads();
    for (int o = 128; o > 0; o >>= 1) { if (t < o) red[t] = fmaxf(red[t], red[t + o]); __syncthreads(); }
    float mx = red[0]; __syncthreads();
    float e = (t < HW_) ? __expf(x - mx) : 0.f;
    red[t] = e; __syncthreads();
    for (int o = 128; o > 0; o >>= 1) { if (t < o) red[t] += red[t + o]; __syncthreads(); }
    float inv = __builtin_amdgcn_rcpf(red[0]);
    if (t < HW_) sm[(b * NCLS + n) * HW_ + t] = e * inv;
}

// ---- K6: out[b,n,c] = sum_hw sm[b,n,hw]*img[b,c,hw]; 16-n tile in LDS ----
__global__ __launch_bounds__(256) void k_pool(const float* __restrict__ sm,
                                              const float* __restrict__ img,
                                              float* __restrict__ out) {
    __shared__ float smt[16 * HW_];
    int cb = blockIdx.x, nt = blockIdx.y, b = blockIdx.z, t = threadIdx.x;
    for (int i = t; i < 16 * HW_; i += 256)
        smt[i] = sm[(b * NCLS + nt * 16) * HW_ + i];
    __syncthreads();
    int c = cb * 256 + t;
    const float* row = img + (b * C_ + c) * HW_;
    float acc[16] = {};
    for (int h4 = 0; h4 < HW_ / 4; ++h4) {
        float4 iv = *(const float4*)(row + h4 * 4);
        #pragma unroll
        for (int nl = 0; nl < 16; ++nl) {
            float4 s4 = *(const float4*)&smt[nl * HW_ + h4 * 4];
            acc[nl] += iv.x * s4.x + iv.y * s4.y + iv.z * s4.z + iv.w * s4.w;
        }
    }
    #pragma unroll
    for (int nl = 0; nl < 16; ++nl)
        out[(b * NCLS + nt * 16 + nl) * C_ + c] = acc[nl];
}

extern "C" void kernel_launch(void* const* d_in, const int* in_sizes, int n_in,
                              void* d_out, int out_size, void* d_ws, size_t ws_size,
                              hipStream_t stream) {
    const float* img  = (const float*)d_in[0];
    const float* wf   = (const float*)d_in[1];
    const float* fc1w = (const float*)d_in[2];
    const float* fc2w = (const float*)d_in[3];
    const float* fc3w = (const float*)d_in[4];
    const float* fc3b = (const float*)d_in[5];
    const float* fc4w = (const float*)d_in[6];
    const float* fc4b = (const float*)d_in[7];
    float* out = (float*)d_out;
    float* ws  = (float*)d_ws;

    float* wp   = ws + WP_OFF;
    float* v    = ws + V_OFF;
    float* bs   = ws + BS_OFF;
    float* imgp = ws + IMGP_OFF;
    float* lg   = ws + LG_OFF;
    float* sm   = ws + SM_OFF;

    hipMemsetAsync(v, 0, ID * sizeof(float), stream);
    hipMemsetAsync(imgp, 0, (size_t)P_ * ID * sizeof(float), stream);

    k_wordp  <<<dim3(320),        256, 0, stream>>>(wf, fc2w, wp);
    k_v      <<<dim3(4, 16),      256, 0, stream>>>(fc3w, fc4w, v);
    k_bs     <<<dim3(1),          256, 0, stream>>>(fc3b, fc4w, fc4b, bs);
    k_fc1    <<<dim3(13, 16, 4),  256, 0, stream>>>(img, fc1w, imgp);
    k_logits <<<dim3(784, 20),    256, 0, stream>>>(imgp, wp, v, bs, lg);
    k_softmax<<<dim3(4, 80),      256, 0, stream>>>(lg, sm);
    k_pool   <<<dim3(8, 5, 4),    256, 0, stream>>>(sm, img, out);
}

// Round 2
// 210.538 us; speedup vs baseline: 1.2106x; 1.2106x over previous
//
#include <hip/hip_runtime.h>

typedef __attribute__((ext_vector_type(8))) short short8;
typedef __attribute__((ext_vector_type(4))) float f32x4;

#define B_   4
#define C_   2048
#define HW_  196
#define P_   784      // B_*HW_
#define NCLS 80
#define WD   300
#define ID   1024

// workspace layout (float offsets) — unchanged from r1 (known-good ws size)
#define WP_OFF   0          // word_p [80][1024]
#define V_OFF    81920      // v [1024]
#define BS_OFF   82944      // bs [1]
#define IMGP_OFF 83968      // img_p [784][1024]
#define LG_OFF   886784     // logits [784][80]
#define SM_OFF   949504     // softmax [4][80][196]

__device__ __forceinline__ unsigned short f2bf(float x) {
    unsigned u = __float_as_uint(x);
    return (unsigned short)((u + 0x7FFFu + ((u >> 16) & 1u)) >> 16);  // RNE
}

// ---- K1: word_p[n][d] = sum_k wf[n,k]*fc2w[d,k] ----
__global__ __launch_bounds__(256) void k_wordp(const float* __restrict__ wf,
                                               const float* __restrict__ fc2w,
                                               float* __restrict__ wp) {
    int idx = blockIdx.x * 256 + threadIdx.x;
    int n = idx >> 10, d = idx & 1023;
    const float4* a = (const float4*)(wf + n * WD);
    const float4* b = (const float4*)(fc2w + d * WD);
    float s = 0.f;
    #pragma unroll 5
    for (int k = 0; k < WD / 4; ++k) {
        float4 x = a[k], y = b[k];
        s += x.x * y.x + x.y * y.y + x.z * y.z + x.w * y.w;
    }
    wp[idx] = s;
}

// ---- K2: v[d] += sum_e fc4w[e]*fc3w[e,d] ----
__global__ __launch_bounds__(256) void k_v(const float* __restrict__ fc3w,
                                           const float* __restrict__ fc4w,
                                           float* __restrict__ v) {
    int d  = blockIdx.x * 256 + threadIdx.x;
    int e0 = blockIdx.y * 64;
    float s = 0.f;
    #pragma unroll 8
    for (int e = e0; e < e0 + 64; ++e) s += fc4w[e] * fc3w[e * ID + d];
    atomicAdd(&v[d], s);
}

// ---- K2b: bs = dot(fc3b, fc4w) + fc4b ----
__global__ __launch_bounds__(256) void k_bs(const float* __restrict__ fc3b,
                                            const float* __restrict__ fc4w,
                                            const float* __restrict__ fc4b,
                                            float* __restrict__ bs) {
    __shared__ float red[256];
    int t = threadIdx.x;
    float s = 0.f;
    for (int i = t; i < ID; i += 256) s += fc3b[i] * fc4w[i];
    red[t] = s; __syncthreads();
    for (int o = 128; o > 0; o >>= 1) { if (t < o) red[t] += red[t + o]; __syncthreads(); }
    if (t == 0) bs[0] = red[0] + fc4b[0];
}

// ---- K3: img_p = A(784x2048) * W^T(2048x1024) via bf16 MFMA ----
// 64x64 tile, BK=64, double-buffered LDS, on-the-fly fp32->bf16.
#define LDT 72   // padded LDS row (bf16 elems): 144B stride -> 16B aligned, bank-balanced
__global__ __launch_bounds__(256) void k_fc1(const float* __restrict__ img,
                                             const float* __restrict__ fc1w,
                                             float* __restrict__ imgp) {
    __shared__ unsigned short As[2][64 * LDT];
    __shared__ unsigned short Bs[2][64 * LDT];
    int t = threadIdx.x;
    int bx = blockIdx.x, by = blockIdx.y;
    int w = t >> 6, l = t & 63;
    int lr = l & 15, lhi = l >> 4;

    // A-load addressing (thread owns row p = bx*64 + l for all K)
    int pA = bx * 64 + l;
    int pAc = pA < P_ ? pA : P_ - 1;
    int bb = pAc / HW_, hw = pAc % HW_;
    const float* aBase = img + (size_t)bb * C_ * HW_ + hw;   // + c*HW_
    // B-load addressing (thread owns row d = t>>2, 16 c's at (t&3)*16)
    int dB = t >> 2, cB = (t & 3) * 16;
    const float* bBase = fc1w + (size_t)(by * 64 + dB) * C_ + cB;

    float ar[16];
    f32x4 br[4];
    f32x4 acc[4];
    #pragma unroll
    for (int j = 0; j < 4; ++j) acc[j] = (f32x4){0.f, 0.f, 0.f, 0.f};

    #define LOAD_AB(kc)                                                        \
        {   int c0 = (kc) * 64;                                                \
            _Pragma("unroll")                                                  \
            for (int pass = 0; pass < 2; ++pass)                               \
                _Pragma("unroll")                                              \
                for (int j = 0; j < 8; ++j)                                    \
                    ar[pass * 8 + j] = aBase[(size_t)(c0 + pass * 32 + w * 8 + j) * HW_]; \
            const f32x4* bp = (const f32x4*)(bBase + c0);                      \
            _Pragma("unroll")                                                  \
            for (int q = 0; q < 4; ++q) br[q] = bp[q];                         \
        }

    #define PACK_WRITE(buf)                                                    \
        {   _Pragma("unroll")                                                  \
            for (int pass = 0; pass < 2; ++pass) {                             \
                short8 av;                                                     \
                _Pragma("unroll")                                              \
                for (int j = 0; j < 8; ++j) av[j] = (short)f2bf(ar[pass * 8 + j]); \
                *reinterpret_cast<short8*>(&As[buf][l * LDT + pass * 32 + w * 8]) = av; \
            }                                                                  \
            _Pragma("unroll")                                                  \
            for (int h = 0; h < 2; ++h) {                                      \
                short8 bv;                                                     \
                _Pragma("unroll")                                              \
                for (int j = 0; j < 4; ++j) {                                  \
                    float fx = br[h * 2 + (j >> 1)][(j & 1) * 2 + 0];          \
                    float fy = br[h * 2 + (j >> 1)][(j & 1) * 2 + 1];          \
                    bv[j * 2] = (short)f2bf(fx); bv[j * 2 + 1] = (short)f2bf(fy); \
                }                                                              \
                *reinterpret_cast<short8*>(&Bs[buf][dB * LDT + cB + h * 8]) = bv; \
            }                                                                  \
        }

    LOAD_AB(0);
    PACK_WRITE(0);
    __syncthreads();

    for (int kc = 0; kc < C_ / 64; ++kc) {
        int cur = kc & 1;
        if (kc < C_ / 64 - 1) LOAD_AB(kc + 1);
        #pragma unroll
        for (int kk = 0; kk < 2; ++kk) {
            short8 af = *reinterpret_cast<const short8*>(
                &As[cur][(w * 16 + lr) * LDT + kk * 32 + lhi * 8]);
            #pragma unroll
            for (int j = 0; j < 4; ++j) {
                short8 bfr = *reinterpret_cast<const short8*>(
                    &Bs[cur][(j * 16 + lr) * LDT + kk * 32 + lhi * 8]);
                acc[j] = __builtin_amdgcn_mfma_f32_16x16x32_bf16(af, bfr, acc[j], 0, 0, 0);
            }
        }
        if (kc < C_ / 64 - 1) PACK_WRITE(cur ^ 1);
        __syncthreads();
    }

    int prow = bx * 64 + w * 16 + lhi * 4;
    int dcol = by * 64 + lr;
    #pragma unroll
    for (int j = 0; j < 4; ++j)
        #pragma unroll
        for (int i = 0; i < 4; ++i)
            if (prow + i < P_) imgp[(size_t)(prow + i) * ID + dcol + j * 16] = acc[j][i];
    #undef LOAD_AB
    #undef PACK_WRITE
}

// ---- K4: logits[p][n] = sum_d tanh(imgp[p,d]*wp[n,d])*v[d] + bs ----
// block = 1 p, wave = 20 n; a,v register-resident (lane owns d in [lane*16, lane*16+16))
__global__ __launch_bounds__(256) void k_logits(const float* __restrict__ imgp,
                                                const float* __restrict__ wp,
                                                const float* __restrict__ v,
                                                const float* __restrict__ bs,
                                                float* __restrict__ lg) {
    int p = blockIdx.x;
    int wv = threadIdx.x >> 6, lane = threadIdx.x & 63;
    const f32x4* a4 = (const f32x4*)(imgp + (size_t)p * ID) + lane * 4;
    const f32x4* v4 = (const f32x4*)v + lane * 4;
    const float K2 = 2.8853900817779268f;  // 2*log2(e)
    f32x4 a2[4], nv2[4];
    float sv = 0.f;
    #pragma unroll
    for (int q = 0; q < 4; ++q) {
        f32x4 aq = a4[q];
        f32x4 vq = v4[q];
        a2[q] = aq * K2;          // exp(2x) = exp2(a2*w)
        nv2[q] = vq * -2.0f;
        sv += vq.x + vq.y + vq.z + vq.w;   // sum tanh*v = sv + sum(nv2*rcp(e+1))
    }
    float bsv = bs[0];
    #pragma unroll 2
    for (int nn = 0; nn < 20; ++nn) {
        int n = wv * 20 + nn;
        const f32x4* w4 = (const f32x4*)(wp + (size_t)n * ID) + lane * 4;
        float s = sv;
        #pragma unroll
        for (int q = 0; q < 4; ++q) {
            f32x4 wq = w4[q];
            float e0 = exp2f(a2[q].x * wq.x);
            float e1 = exp2f(a2[q].y * wq.y);
            float e2 = exp2f(a2[q].z * wq.z);
            float e3 = exp2f(a2[q].w * wq.w);
            s += nv2[q].x * __builtin_amdgcn_rcpf(e0 + 1.f);
            s += nv2[q].y * __builtin_amdgcn_rcpf(e1 + 1.f);
            s += nv2[q].z * __builtin_amdgcn_rcpf(e2 + 1.f);
            s += nv2[q].w * __builtin_amdgcn_rcpf(e3 + 1.f);
        }
        #pragma unroll
        for (int off = 32; off > 0; off >>= 1) s += __shfl_xor(s, off, 64);
        if (lane == 0) lg[p * NCLS + n] = s + bsv;
    }
}

// ---- K5: softmax over 196 positions per (b,n) ----
__global__ __launch_bounds__(256) void k_softmax(const float* __restrict__ lg,
                                                 float* __restrict__ sm) {
    __shared__ float red[256];
    int b = blockIdx.x, n = blockIdx.y, t = threadIdx.x;
    float x = (t < HW_) ? lg[(b * HW_ + t) * NCLS + n] : -1e30f;
    red[t] = x; __syncthreads();
    for (int o = 128; o > 0; o >>= 1) { if (t < o) red[t] = fmaxf(red[t], red[t + o]); __syncthreads(); }
    float mx = red[0]; __syncthreads();
    float e = (t < HW_) ? __expf(x - mx) : 0.f;
    red[t] = e; __syncthreads();
    for (int o = 128; o > 0; o >>= 1) { if (t < o) red[t] += red[t + o]; __syncthreads(); }
    float inv = __builtin_amdgcn_rcpf(red[0]);
    if (t < HW_) sm[(b * NCLS + n) * HW_ + t] = e * inv;
}

// ---- K6: out[b,n,c] = sum_hw sm[b,n,hw]*img[b,c,hw] ----
__global__ __launch_bounds__(256) void k_pool(const float* __restrict__ sm,
                                              const float* __restrict__ img,
                                              float* __restrict__ out) {
    __shared__ float smt[16 * HW_];
    int cb = blockIdx.x, nt = blockIdx.y, b = blockIdx.z, t = threadIdx.x;
    for (int i = t; i < 16 * HW_; i += 256)
        smt[i] = sm[(b * NCLS + nt * 16) * HW_ + i];
    __syncthreads();
    int c = cb * 256 + t;
    const float* row = img + (b * C_ + c) * HW_;
    float acc[16] = {};
    for (int h4 = 0; h4 < HW_ / 4; ++h4) {
        float4 iv = *(const float4*)(row + h4 * 4);
        #pragma unroll
        for (int nl = 0; nl < 16; ++nl) {
            float4 s4 = *(const float4*)&smt[nl * HW_ + h4 * 4];
            acc[nl] += iv.x * s4.x + iv.y * s4.y + iv.z * s4.z + iv.w * s4.w;
        }
    }
    #pragma unroll
    for (int nl = 0; nl < 16; ++nl)
        out[(b * NCLS + nt * 16 + nl) * C_ + c] = acc[nl];
}

extern "C" void kernel_launch(void* const* d_in, const int* in_sizes, int n_in,
                              void* d_out, int out_size, void* d_ws, size_t ws_size,
                              hipStream_t stream) {
    const float* img  = (const float*)d_in[0];
    const float* wf   = (const float*)d_in[1];
    const float* fc1w = (const float*)d_in[2];
    const float* fc2w = (const float*)d_in[3];
    const float* fc3w = (const float*)d_in[4];
    const float* fc3b = (const float*)d_in[5];
    const float* fc4w = (const float*)d_in[6];
    const float* fc4b = (const float*)d_in[7];
    float* out = (float*)d_out;
    float* ws  = (float*)d_ws;

    float* wp   = ws + WP_OFF;
    float* v    = ws + V_OFF;
    float* bs   = ws + BS_OFF;
    float* imgp = ws + IMGP_OFF;
    float* lg   = ws + LG_OFF;
    float* sm   = ws + SM_OFF;

    hipMemsetAsync(v, 0, ID * sizeof(float), stream);

    k_wordp  <<<dim3(320),       256, 0, stream>>>(wf, fc2w, wp);
    k_v      <<<dim3(4, 16),     256, 0, stream>>>(fc3w, fc4w, v);
    k_bs     <<<dim3(1),         256, 0, stream>>>(fc3b, fc4w, fc4b, bs);
    k_fc1    <<<dim3(13, 16),    256, 0, stream>>>(img, fc1w, imgp);
    k_logits <<<dim3(784),       256, 0, stream>>>(imgp, wp, v, bs, lg);
    k_softmax<<<dim3(4, 80),     256, 0, stream>>>(lg, sm);
    k_pool   <<<dim3(8, 5, 4),   256, 0, stream>>>(sm, img, out);
}

// Round 3
// 188.902 us; speedup vs baseline: 1.3493x; 1.1145x over previous
//
#include <hip/hip_runtime.h>

typedef __attribute__((ext_vector_type(8))) short short8;
typedef __attribute__((ext_vector_type(4))) float f32x4;

#define B_   4
#define C_   2048
#define HW_  196
#define P_   784      // B_*HW_
#define NCLS 80
#define WD   300
#define ID   1024

// workspace layout (float offsets)
#define WP_OFF    0          // word_p [80][1024]
#define V_OFF     81920      // v [1024]
#define BS_OFF    82944      // bs [1]
#define IMGP_OFF  83968      // img_p partials [4][784][1024]
#define LG_OFF    3295232    // logits [784][80]
#define SM_OFF    3357952    // softmax [4][80][196]
#define ABF_BYTE  13682688   // Abf [784][2048] bf16
#define WBF_BYTE  16893952   // Wbf [1024][2048] bf16

__device__ __forceinline__ unsigned short f2bf(float x) {
    unsigned u = __float_as_uint(x);
    return (unsigned short)((u + 0x7FFFu + ((u >> 16) & 1u)) >> 16);  // RNE
}

// ---- cvtW: fc1w fp32 -> bf16, same layout [d][c] ----
typedef __attribute__((ext_vector_type(4))) unsigned short u16x4;
__global__ __launch_bounds__(256) void k_cvtW(const float* __restrict__ w,
                                              unsigned short* __restrict__ wbf) {
    int i = (blockIdx.x * 256 + threadIdx.x) * 4;
    float4 v = *(const float4*)(w + i);
    u16x4 r = {f2bf(v.x), f2bf(v.y), f2bf(v.z), f2bf(v.w)};
    *(u16x4*)(wbf + i) = r;
}

// ---- cvtA: img[b][c][hw] fp32 -> Abf[p=b*196+hw][c] bf16 (LDS transpose) ----
__global__ __launch_bounds__(256) void k_cvtA(const float* __restrict__ img,
                                              unsigned short* __restrict__ abf) {
    __shared__ unsigned short tile[HW_][65];   // [hw][c-local]
    int b = blockIdx.y, c0 = blockIdx.x * 64, t = threadIdx.x;
    for (int idx = t; idx < 64 * HW_; idx += 256) {
        int c = idx / HW_, hw = idx - c * HW_;
        tile[hw][c] = f2bf(img[((size_t)b * C_ + c0 + c) * HW_ + hw]);
    }
    __syncthreads();
    for (int idx = t; idx < 64 * HW_; idx += 256) {
        int hw = idx >> 6, c = idx & 63;
        abf[((size_t)b * HW_ + hw) * C_ + c0 + c] = tile[hw][c];
    }
}

// ---- K1: word_p[n][d] = sum_k wf[n,k]*fc2w[d,k] ----
__global__ __launch_bounds__(256) void k_wordp(const float* __restrict__ wf,
                                               const float* __restrict__ fc2w,
                                               float* __restrict__ wp) {
    int idx = blockIdx.x * 256 + threadIdx.x;
    int n = idx >> 10, d = idx & 1023;
    const float4* a = (const float4*)(wf + n * WD);
    const float4* b = (const float4*)(fc2w + d * WD);
    float s = 0.f;
    #pragma unroll 5
    for (int k = 0; k < WD / 4; ++k) {
        float4 x = a[k], y = b[k];
        s += x.x * y.x + x.y * y.y + x.z * y.z + x.w * y.w;
    }
    wp[idx] = s;
}

// ---- K2: v[d] += sum_e fc4w[e]*fc3w[e,d] ----
__global__ __launch_bounds__(256) void k_v(const float* __restrict__ fc3w,
                                           const float* __restrict__ fc4w,
                                           float* __restrict__ v) {
    int d  = blockIdx.x * 256 + threadIdx.x;
    int e0 = blockIdx.y * 64;
    float s = 0.f;
    #pragma unroll 8
    for (int e = e0; e < e0 + 64; ++e) s += fc4w[e] * fc3w[e * ID + d];
    atomicAdd(&v[d], s);
}

// ---- K2b: bs = dot(fc3b, fc4w) + fc4b ----
__global__ __launch_bounds__(256) void k_bs(const float* __restrict__ fc3b,
                                            const float* __restrict__ fc4w,
                                            const float* __restrict__ fc4b,
                                            float* __restrict__ bs) {
    __shared__ float red[256];
    int t = threadIdx.x;
    float s = 0.f;
    for (int i = t; i < ID; i += 256) s += fc3b[i] * fc4w[i];
    red[t] = s; __syncthreads();
    for (int o = 128; o > 0; o >>= 1) { if (t < o) red[t] += red[t + o]; __syncthreads(); }
    if (t == 0) bs[0] = red[0] + fc4b[0];
}

// ---- K3: img_p partial[bz] = Abf(784x2048) * Wbf^T, split-K=4, bf16 MFMA ----
#define LDT 72   // padded LDS row (bf16 elems)
__global__ __launch_bounds__(256) void k_fc1(const unsigned short* __restrict__ Abf,
                                             const unsigned short* __restrict__ Wbf,
                                             float* __restrict__ imgp4) {
    __shared__ unsigned short As[2][64 * LDT];
    __shared__ unsigned short Bs[2][64 * LDT];
    int t = threadIdx.x;
    int bx = blockIdx.x, by = blockIdx.y, bz = blockIdx.z;
    int w = t >> 6, l = t & 63;
    int lr = l & 15, lhi = l >> 4;
    int row = t >> 2, cq = (t & 3) * 16;

    int pA = bx * 64 + row;
    int pAc = pA < P_ ? pA : P_ - 1;
    const unsigned short* aBase = Abf + (size_t)pAc * C_ + bz * 512 + cq;
    const unsigned short* bBase = Wbf + (size_t)(by * 64 + row) * C_ + bz * 512 + cq;

    short8 ra0, ra1, rb0, rb1;
    f32x4 acc[4];
    #pragma unroll
    for (int j = 0; j < 4; ++j) acc[j] = (f32x4){0.f, 0.f, 0.f, 0.f};

    #define LOADR(kc) { \
        const short8* ap = (const short8*)(aBase + (kc) * 64); \
        const short8* bp = (const short8*)(bBase + (kc) * 64); \
        ra0 = ap[0]; ra1 = ap[1]; rb0 = bp[0]; rb1 = bp[1]; }
    #define WRITES(buf) { \
        *(short8*)&As[buf][row * LDT + cq]     = ra0; \
        *(short8*)&As[buf][row * LDT + cq + 8] = ra1; \
        *(short8*)&Bs[buf][row * LDT + cq]     = rb0; \
        *(short8*)&Bs[buf][row * LDT + cq + 8] = rb1; }

    LOADR(0);
    WRITES(0);
    __syncthreads();

    for (int kc = 0; kc < 8; ++kc) {
        int cur = kc & 1;
        if (kc < 7) LOADR(kc + 1);
        #pragma unroll
        for (int kk = 0; kk < 2; ++kk) {
            short8 af = *reinterpret_cast<const short8*>(
                &As[cur][(w * 16 + lr) * LDT + kk * 32 + lhi * 8]);
            #pragma unroll
            for (int j = 0; j < 4; ++j) {
                short8 bfr = *reinterpret_cast<const short8*>(
                    &Bs[cur][(j * 16 + lr) * LDT + kk * 32 + lhi * 8]);
                acc[j] = __builtin_amdgcn_mfma_f32_16x16x32_bf16(af, bfr, acc[j], 0, 0, 0);
            }
        }
        if (kc < 7) WRITES(cur ^ 1);
        __syncthreads();
    }
    #undef LOADR
    #undef WRITES

    float* outp = imgp4 + (size_t)bz * (P_ * ID);
    int prow = bx * 64 + w * 16 + lhi * 4;
    int dcol = by * 64 + lr;
    #pragma unroll
    for (int j = 0; j < 4; ++j)
        #pragma unroll
        for (int i = 0; i < 4; ++i)
            if (prow + i < P_) outp[(size_t)(prow + i) * ID + dcol + j * 16] = acc[j][i];
}

// ---- K4: logits[p][n] = sum_d tanh(imgp[p,d]*wp[n,d])*v[d] + bs ----
__global__ __launch_bounds__(256) void k_logits(const float* __restrict__ imgp4,
                                                const float* __restrict__ wp,
                                                const float* __restrict__ v,
                                                const float* __restrict__ bs,
                                                float* __restrict__ lg) {
    int p = blockIdx.x;
    int wv = threadIdx.x >> 6, lane = threadIdx.x & 63;
    const int S4 = P_ * ID / 4;   // slab stride in f32x4
    const f32x4* a0 = (const f32x4*)(imgp4 + (size_t)p * ID) + lane * 4;
    const f32x4* v4 = (const f32x4*)v + lane * 4;
    const float K2 = 2.8853900817779268f;  // 2*log2(e)
    f32x4 a2[4], nv2[4];
    float sv = 0.f;
    #pragma unroll
    for (int q = 0; q < 4; ++q) {
        f32x4 aq = a0[q] + a0[S4 + q] + a0[2 * S4 + q] + a0[3 * S4 + q];
        f32x4 vq = v4[q];
        a2[q] = aq * K2;
        nv2[q] = vq * -2.0f;
        sv += vq.x + vq.y + vq.z + vq.w;
    }
    float bsv = bs[0];
    #pragma unroll 2
    for (int nn = 0; nn < 20; ++nn) {
        int n = wv * 20 + nn;
        const f32x4* w4 = (const f32x4*)(wp + (size_t)n * ID) + lane * 4;
        float s = sv;
        #pragma unroll
        for (int q = 0; q < 4; ++q) {
            f32x4 wq = w4[q];
            float e0 = __builtin_amdgcn_exp2f(a2[q].x * wq.x);
            float e1 = __builtin_amdgcn_exp2f(a2[q].y * wq.y);
            float e2 = __builtin_amdgcn_exp2f(a2[q].z * wq.z);
            float e3 = __builtin_amdgcn_exp2f(a2[q].w * wq.w);
            s += nv2[q].x * __builtin_amdgcn_rcpf(e0 + 1.f);
            s += nv2[q].y * __builtin_amdgcn_rcpf(e1 + 1.f);
            s += nv2[q].z * __builtin_amdgcn_rcpf(e2 + 1.f);
            s += nv2[q].w * __builtin_amdgcn_rcpf(e3 + 1.f);
        }
        #pragma unroll
        for (int off = 32; off > 0; off >>= 1) s += __shfl_xor(s, off, 64);
        if (lane == 0) lg[p * NCLS + n] = s + bsv;
    }
}

// ---- K5: softmax over 196 positions per (b,n) ----
__global__ __launch_bounds__(256) void k_softmax(const float* __restrict__ lg,
                                                 float* __restrict__ sm) {
    __shared__ float red[256];
    int b = blockIdx.x, n = blockIdx.y, t = threadIdx.x;
    float x = (t < HW_) ? lg[(b * HW_ + t) * NCLS + n] : -1e30f;
    red[t] = x; __syncthreads();
    for (int o = 128; o > 0; o >>= 1) { if (t < o) red[t] = fmaxf(red[t], red[t + o]); __syncthreads(); }
    float mx = red[0]; __syncthreads();
    float e = (t < HW_) ? __expf(x - mx) : 0.f;
    red[t] = e; __syncthreads();
    for (int o = 128; o > 0; o >>= 1) { if (t < o) red[t] += red[t + o]; __syncthreads(); }
    float inv = __builtin_amdgcn_rcpf(red[0]);
    if (t < HW_) sm[(b * NCLS + n) * HW_ + t] = e * inv;
}

// ---- K6: out[b,n,c] = sum_hw sm[b,n,hw]*img[b,c,hw] ----
__global__ __launch_bounds__(256) void k_pool(const float* __restrict__ sm,
                                              const float* __restrict__ img,
                                              float* __restrict__ out) {
    __shared__ float smt[16 * HW_];
    int cb = blockIdx.x, nt = blockIdx.y, b = blockIdx.z, t = threadIdx.x;
    for (int i = t; i < 16 * HW_; i += 256)
        smt[i] = sm[(b * NCLS + nt * 16) * HW_ + i];
    __syncthreads();
    int c = cb * 256 + t;
    const float* row = img + (b * C_ + c) * HW_;
    float acc[16] = {};
    for (int h4 = 0; h4 < HW_ / 4; ++h4) {
        float4 iv = *(const float4*)(row + h4 * 4);
        #pragma unroll
        for (int nl = 0; nl < 16; ++nl) {
            float4 s4 = *(const float4*)&smt[nl * HW_ + h4 * 4];
            acc[nl] += iv.x * s4.x + iv.y * s4.y + iv.z * s4.z + iv.w * s4.w;
        }
    }
    #pragma unroll
    for (int nl = 0; nl < 16; ++nl)
        out[(b * NCLS + nt * 16 + nl) * C_ + c] = acc[nl];
}

extern "C" void kernel_launch(void* const* d_in, const int* in_sizes, int n_in,
                              void* d_out, int out_size, void* d_ws, size_t ws_size,
                              hipStream_t stream) {
    const float* img  = (const float*)d_in[0];
    const float* wf   = (const float*)d_in[1];
    const float* fc1w = (const float*)d_in[2];
    const float* fc2w = (const float*)d_in[3];
    const float* fc3w = (const float*)d_in[4];
    const float* fc3b = (const float*)d_in[5];
    const float* fc4w = (const float*)d_in[6];
    const float* fc4b = (const float*)d_in[7];
    float* out = (float*)d_out;
    float* ws  = (float*)d_ws;

    float* wp    = ws + WP_OFF;
    float* v     = ws + V_OFF;
    float* bs    = ws + BS_OFF;
    float* imgp4 = ws + IMGP_OFF;
    float* lg    = ws + LG_OFF;
    float* sm    = ws + SM_OFF;
    unsigned short* Abf = (unsigned short*)((char*)d_ws + ABF_BYTE);
    unsigned short* Wbf = (unsigned short*)((char*)d_ws + WBF_BYTE);

    hipMemsetAsync(v, 0, ID * sizeof(float), stream);

    k_cvtW   <<<dim3(2048),      256, 0, stream>>>(fc1w, Wbf);
    k_cvtA   <<<dim3(32, 4),     256, 0, stream>>>(img, Abf);
    k_wordp  <<<dim3(320),       256, 0, stream>>>(wf, fc2w, wp);
    k_v      <<<dim3(4, 16),     256, 0, stream>>>(fc3w, fc4w, v);
    k_bs     <<<dim3(1),         256, 0, stream>>>(fc3b, fc4w, fc4b, bs);
    k_fc1    <<<dim3(13, 16, 4), 256, 0, stream>>>(Abf, Wbf, imgp4);
    k_logits <<<dim3(784),       256, 0, stream>>>(imgp4, wp, v, bs, lg);
    k_softmax<<<dim3(4, 80),     256, 0, stream>>>(lg, sm);
    k_pool   <<<dim3(8, 5, 4),   256, 0, stream>>>(sm, img, out);
}

// Round 4
// 169.451 us; speedup vs baseline: 1.5041x; 1.1148x over previous
//
#include <hip/hip_runtime.h>

typedef __attribute__((ext_vector_type(8))) short short8;
typedef __attribute__((ext_vector_type(4))) float f32x4;
typedef __attribute__((ext_vector_type(4))) unsigned short u16x4;

#define B_   4
#define C_   2048
#define HW_  196
#define P_   784      // B_*HW_
#define NCLS 80
#define WD   300
#define ID   1024

// workspace layout (float offsets)
#define WP_OFF    0          // word_p [80][1024]
#define V_OFF     81920      // v [1024]
#define BS_OFF    82944      // bs [1]
#define IMGP_OFF  83968      // img_p partials [4][784][1024]
#define LG_OFF    3295232    // logits [784][80]
#define VPART_OFF 3357952    // vpart [16][1024]
#define ABF_BYTE  13748224   // Abf [784][2048] bf16
#define WBF_BYTE  16959488   // Wbf [1024][2048] bf16

__device__ __forceinline__ unsigned short f2bf(float x) {
    unsigned u = __float_as_uint(x);
    return (unsigned short)((u + 0x7FFFu + ((u >> 16) & 1u)) >> 16);  // RNE
}

// ---- K_prep: fused independent preprocessing via block-range dispatch ----
// blocks [0,320)   : word_p[n][d] = wf[n,:] . fc2w[d,:]
// blocks [320,832) : cvtW  fc1w fp32 -> Wbf bf16 (same [d][c] layout)
// blocks [832,960) : cvtA  img[b][c][hw] -> Abf[p][c] bf16 (LDS transpose)
// blocks [960,1024): vpart[ec][d] = sum_{e in chunk ec} fc4w[e]*fc3w[e,d]
__global__ __launch_bounds__(256) void k_prep(const float* __restrict__ img,
                                              const float* __restrict__ wf,
                                              const float* __restrict__ fc1w,
                                              const float* __restrict__ fc2w,
                                              const float* __restrict__ fc3w,
                                              const float* __restrict__ fc4w,
                                              unsigned short* __restrict__ abf,
                                              unsigned short* __restrict__ wbf,
                                              float* __restrict__ wp,
                                              float* __restrict__ vpart) {
    __shared__ unsigned short tile[HW_][68];
    int bid = blockIdx.x, t = threadIdx.x;
    if (bid < 320) {                       // ---- word_p ----
        int idx = bid * 256 + t;
        int n = idx >> 10, d = idx & 1023;
        const float4* a = (const float4*)(wf + n * WD);
        const float4* b = (const float4*)(fc2w + d * WD);
        float s = 0.f;
        #pragma unroll 5
        for (int k = 0; k < WD / 4; ++k) {
            float4 x = a[k], y = b[k];
            s += x.x * y.x + x.y * y.y + x.z * y.z + x.w * y.w;
        }
        wp[idx] = s;
    } else if (bid < 832) {                // ---- cvtW ----
        size_t base = (size_t)(bid - 320) * 4096 + (size_t)t * 16;
        #pragma unroll
        for (int j = 0; j < 4; ++j) {
            float4 v4 = *(const float4*)(fc1w + base + j * 4);
            u16x4 r = {f2bf(v4.x), f2bf(v4.y), f2bf(v4.z), f2bf(v4.w)};
            *(u16x4*)(wbf + base + j * 4) = r;
        }
    } else if (bid < 960) {                // ---- cvtA ----
        int bc = bid - 832;
        int c0 = (bc >> 2) * 64, b = bc & 3;
        for (int idx = t; idx < 64 * HW_; idx += 256) {
            int c = idx / HW_, hw = idx - c * HW_;
            tile[hw][c] = f2bf(img[((size_t)b * C_ + c0 + c) * HW_ + hw]);
        }
        __syncthreads();
        for (int q = t; q < 16 * HW_; q += 256) {   // 4-wide stores
            int hw = q >> 4, c4 = (q & 15) * 4;
            u16x4 r = *(const u16x4*)&tile[hw][c4];
            *(u16x4*)(abf + ((size_t)b * HW_ + hw) * C_ + c0 + c4) = r;
        }
    } else {                               // ---- vpart ----
        int idx = bid - 960;
        int ec = idx >> 2;
        int d = (idx & 3) * 256 + t;
        float s = 0.f;
        #pragma unroll 8
        for (int e = ec * 64; e < ec * 64 + 64; ++e) s += fc4w[e] * fc3w[e * ID + d];
        vpart[ec * ID + d] = s;
    }
}

// ---- K_fc1: img_p partial[bz] = Abf(784x2048) * Wbf^T, split-K=4, bf16 MFMA ----
// block (0,0,0) additionally finalizes v = sum_slabs vpart and bs = fc3b.fc4w + fc4b
#define LDT 72
__global__ __launch_bounds__(256) void k_fc1(const unsigned short* __restrict__ Abf,
                                             const unsigned short* __restrict__ Wbf,
                                             const float* __restrict__ fc3b,
                                             const float* __restrict__ fc4w,
                                             const float* __restrict__ fc4b,
                                             const float* __restrict__ vpart,
                                             float* __restrict__ imgp4,
                                             float* __restrict__ v,
                                             float* __restrict__ bs) {
    __shared__ unsigned short As[2][64 * LDT];
    __shared__ unsigned short Bs[2][64 * LDT];
    int t = threadIdx.x;
    int bx = blockIdx.x, by = blockIdx.y, bz = blockIdx.z;
    int w = t >> 6, l = t & 63;
    int lr = l & 15, lhi = l >> 4;
    int row = t >> 2, cq = (t & 3) * 16;

    int pA = bx * 64 + row;
    int pAc = pA < P_ ? pA : P_ - 1;
    const unsigned short* aBase = Abf + (size_t)pAc * C_ + bz * 512 + cq;
    const unsigned short* bBase = Wbf + (size_t)(by * 64 + row) * C_ + bz * 512 + cq;

    short8 ra0, ra1, rb0, rb1;
    f32x4 acc[4];
    #pragma unroll
    for (int j = 0; j < 4; ++j) acc[j] = (f32x4){0.f, 0.f, 0.f, 0.f};

    #define LOADR(kc) { \
        const short8* ap = (const short8*)(aBase + (kc) * 64); \
        const short8* bp = (const short8*)(bBase + (kc) * 64); \
        ra0 = ap[0]; ra1 = ap[1]; rb0 = bp[0]; rb1 = bp[1]; }
    #define WRITES(buf) { \
        *(short8*)&As[buf][row * LDT + cq]     = ra0; \
        *(short8*)&As[buf][row * LDT + cq + 8] = ra1; \
        *(short8*)&Bs[buf][row * LDT + cq]     = rb0; \
        *(short8*)&Bs[buf][row * LDT + cq + 8] = rb1; }

    LOADR(0);
    WRITES(0);
    __syncthreads();

    for (int kc = 0; kc < 8; ++kc) {
        int cur = kc & 1;
        if (kc < 7) LOADR(kc + 1);
        #pragma unroll
        for (int kk = 0; kk < 2; ++kk) {
            short8 af = *reinterpret_cast<const short8*>(
                &As[cur][(w * 16 + lr) * LDT + kk * 32 + lhi * 8]);
            #pragma unroll
            for (int j = 0; j < 4; ++j) {
                short8 bfr = *reinterpret_cast<const short8*>(
                    &Bs[cur][(j * 16 + lr) * LDT + kk * 32 + lhi * 8]);
                acc[j] = __builtin_amdgcn_mfma_f32_16x16x32_bf16(af, bfr, acc[j], 0, 0, 0);
            }
        }
        if (kc < 7) WRITES(cur ^ 1);
        __syncthreads();
    }
    #undef LOADR
    #undef WRITES

    float* outp = imgp4 + (size_t)bz * (P_ * ID);
    int prow = bx * 64 + w * 16 + lhi * 4;
    int dcol = by * 64 + lr;
    #pragma unroll
    for (int j = 0; j < 4; ++j)
        #pragma unroll
        for (int i = 0; i < 4; ++i)
            if (prow + i < P_) outp[(size_t)(prow + i) * ID + dcol + j * 16] = acc[j][i];

    if (bx == 0 && by == 0 && bz == 0) {   // finalize v and bs (before k_logits)
        for (int d = t; d < ID; d += 256) {
            float s = 0.f;
            #pragma unroll
            for (int k = 0; k < 16; ++k) s += vpart[k * ID + d];
            v[d] = s;
        }
        float s = 0.f;
        for (int i = t; i < ID; i += 256) s += fc3b[i] * fc4w[i];
        __syncthreads();
        float* red = (float*)&As[0][0];
        red[t] = s; __syncthreads();
        for (int o = 128; o > 0; o >>= 1) { if (t < o) red[t] += red[t + o]; __syncthreads(); }
        if (t == 0) bs[0] = red[0] + fc4b[0];
    }
}

// ---- K_logits: lg[p][n] = sum_d tanh(imgp[p,d]*wp[n,d])*v[d] + bs ----
// grid (196,2): 4 waves = 4 p's; 40 n per block, wp staged via LDS in 8-row chunks.
// lane owns d = q*256 + lane*4 (q=0..3) -> conflict-free b128 LDS reads, coalesced global.
__global__ __launch_bounds__(256) void k_logits(const float* __restrict__ imgp4,
                                                const float* __restrict__ wp,
                                                const float* __restrict__ v,
                                                const float* __restrict__ bs,
                                                float* __restrict__ lg) {
    __shared__ float wpl[8 * ID];
    int bx = blockIdx.x, by = blockIdx.y;
    int t = threadIdx.x, wv = t >> 6, lane = t & 63;
    int p = bx * 4 + wv;
    const int S = P_ * ID;
    const float* ap = imgp4 + (size_t)p * ID;
    const float K2 = 2.8853900817779268f;  // 2*log2(e)
    f32x4 a2[4], nv2[4];
    float sv = 0.f;
    #pragma unroll
    for (int q = 0; q < 4; ++q) {
        int d = q * 256 + lane * 4;
        f32x4 aq = *(const f32x4*)(ap + d);
        aq += *(const f32x4*)(ap + S + d);
        aq += *(const f32x4*)(ap + 2 * S + d);
        aq += *(const f32x4*)(ap + 3 * S + d);
        f32x4 vq = *(const f32x4*)(v + d);
        a2[q] = aq * K2;
        nv2[q] = vq * -2.0f;
        sv += vq.x + vq.y + vq.z + vq.w;
    }
    float bsv = bs[0];
    int n0 = by * 40;
    for (int ch = 0; ch < 5; ++ch) {
        __syncthreads();
        #pragma unroll
        for (int j = 0; j < 8; ++j) {      // stage 8 wp rows (32KB)
            int flat = t * 32 + j * 4;
            *(f32x4*)(wpl + flat) =
                *(const f32x4*)(wp + (size_t)(n0 + ch * 8 + (flat >> 10)) * ID + (flat & 1023));
        }
        __syncthreads();
        #pragma unroll
        for (int r = 0; r < 8; ++r) {
            float s = sv;
            #pragma unroll
            for (int q = 0; q < 4; ++q) {
                f32x4 wq = *(const f32x4*)(wpl + r * ID + q * 256 + lane * 4);
                float e0 = __builtin_amdgcn_exp2f(a2[q].x * wq.x);
                float e1 = __builtin_amdgcn_exp2f(a2[q].y * wq.y);
                float e2 = __builtin_amdgcn_exp2f(a2[q].z * wq.z);
                float e3 = __builtin_amdgcn_exp2f(a2[q].w * wq.w);
                s += nv2[q].x * __builtin_amdgcn_rcpf(e0 + 1.f);
                s += nv2[q].y * __builtin_amdgcn_rcpf(e1 + 1.f);
                s += nv2[q].z * __builtin_amdgcn_rcpf(e2 + 1.f);
                s += nv2[q].w * __builtin_amdgcn_rcpf(e3 + 1.f);
            }
            #pragma unroll
            for (int off = 32; off > 0; off >>= 1) s += __shfl_xor(s, off, 64);
            if (lane == 0) lg[p * NCLS + n0 + ch * 8 + r] = s + bsv;
        }
    }
}

// ---- K_pool: fused softmax (over 196 positions per (b,n)) + weighted pooling ----
__global__ __launch_bounds__(256) void k_pool(const float* __restrict__ lg,
                                              const float* __restrict__ img,
                                              float* __restrict__ out) {
    __shared__ float smt[16 * HW_];
    int cb = blockIdx.x, nt = blockIdx.y, b = blockIdx.z, t = threadIdx.x;
    int n_l = t >> 4, seg = t & 15;
    int n = nt * 16 + n_l;
    float xr[13];
    float mx = -1e30f;
    #pragma unroll
    for (int j = 0; j < 13; ++j) {
        int hw = seg + j * 16;
        float x = (hw < HW_) ? lg[(size_t)(b * HW_ + hw) * NCLS + n] : -1e30f;
        xr[j] = x; mx = fmaxf(mx, x);
    }
    #pragma unroll
    for (int o = 8; o > 0; o >>= 1) mx = fmaxf(mx, __shfl_xor(mx, o, 16));
    float sum = 0.f;
    #pragma unroll
    for (int j = 0; j < 13; ++j) {
        int hw = seg + j * 16;
        float e = (hw < HW_) ? __expf(xr[j] - mx) : 0.f;
        xr[j] = e; sum += e;
    }
    #pragma unroll
    for (int o = 8; o > 0; o >>= 1) sum += __shfl_xor(sum, o, 16);
    float inv = __builtin_amdgcn_rcpf(sum);
    #pragma unroll
    for (int j = 0; j < 13; ++j) {
        int hw = seg + j * 16;
        if (hw < HW_) smt[n_l * HW_ + hw] = xr[j] * inv;
    }
    __syncthreads();

    int c = cb * 256 + t;
    const float* row = img + ((size_t)b * C_ + c) * HW_;
    float acc[16] = {};
    for (int h4 = 0; h4 < HW_ / 4; ++h4) {
        float4 iv = *(const float4*)(row + h4 * 4);
        #pragma unroll
        for (int nl = 0; nl < 16; ++nl) {
            float4 s4 = *(const float4*)&smt[nl * HW_ + h4 * 4];
            acc[nl] += iv.x * s4.x + iv.y * s4.y + iv.z * s4.z + iv.w * s4.w;
        }
    }
    #pragma unroll
    for (int nl = 0; nl < 16; ++nl)
        out[((size_t)b * NCLS + nt * 16 + nl) * C_ + c] = acc[nl];
}

extern "C" void kernel_launch(void* const* d_in, const int* in_sizes, int n_in,
                              void* d_out, int out_size, void* d_ws, size_t ws_size,
                              hipStream_t stream) {
    const float* img  = (const float*)d_in[0];
    const float* wf   = (const float*)d_in[1];
    const float* fc1w = (const float*)d_in[2];
    const float* fc2w = (const float*)d_in[3];
    const float* fc3w = (const float*)d_in[4];
    const float* fc3b = (const float*)d_in[5];
    const float* fc4w = (const float*)d_in[6];
    const float* fc4b = (const float*)d_in[7];
    float* out = (float*)d_out;
    float* ws  = (float*)d_ws;

    float* wp    = ws + WP_OFF;
    float* v     = ws + V_OFF;
    float* bs    = ws + BS_OFF;
    float* imgp4 = ws + IMGP_OFF;
    float* lg    = ws + LG_OFF;
    float* vpart = ws + VPART_OFF;
    unsigned short* Abf = (unsigned short*)((char*)d_ws + ABF_BYTE);
    unsigned short* Wbf = (unsigned short*)((char*)d_ws + WBF_BYTE);

    k_prep   <<<dim3(1024),      256, 0, stream>>>(img, wf, fc1w, fc2w, fc3w, fc4w,
                                                   Abf, Wbf, wp, vpart);
    k_fc1    <<<dim3(13, 16, 4), 256, 0, stream>>>(Abf, Wbf, fc3b, fc4w, fc4b, vpart,
                                                   imgp4, v, bs);
    k_logits <<<dim3(196, 2),    256, 0, stream>>>(imgp4, wp, v, bs, lg);
    k_pool   <<<dim3(8, 5, 4),   256, 0, stream>>>(lg, img, out);
}